// Round 1
// baseline (61.381 us; speedup 1.0000x reference)
//
#include <hip/hip_runtime.h>
#include <stdint.h>

// Problem constants
static constexpr int NB = 16;     // batch
static constexpr int CI = 32;     // in channels
static constexpr int CO = 64;     // out channels
static constexpr int HI = 224, WI = 224;
static constexpr int HO = 112, WO = 112;
static constexpr float EPS = 1e-5f;

typedef _Float16 h2 __attribute__((ext_vector_type(2)));

__device__ __forceinline__ h2 as_h2(uint32_t u) {
    union { uint32_t u; h2 h; } c; c.u = u; return c.h;
}
__device__ __forceinline__ uint32_t pack_h2(float a, float b) {
    union { uint32_t u; h2 h; } c;
    c.h = (h2){(_Float16)a, (_Float16)b};
    return c.u;
}

// One fused kernel: per block = (b, output row-pair g, 64-wide ow tile).
//   Phase 0: stage weight-derived constants to LDS (redundant per block; wbody/wds
//            are 82 KB total -> L2-resident after the first blocks).
//   Phase 1: read the 5 needed input rows of x once, derive sign-bit masks (s_xb)
//            and 2x2 avgpool half2 ci-pairs (s_avg) directly into LDS.
//   Phase 2: exactly the proven main_kernel compute (popc body + fdot2 downsample),
//            looped over the 2 output rows.
// No workspace, no intermediate HBM tensors, single __syncthreads.
__global__ __launch_bounds__(256) void fused_kernel(
    const float* __restrict__ x, const float* __restrict__ wbody,
    const float* __restrict__ g1, const float* __restrict__ b1,
    const float* __restrict__ m1, const float* __restrict__ v1,
    const float* __restrict__ wds,
    const float* __restrict__ g2, const float* __restrict__ b2,
    const float* __restrict__ m2, const float* __restrict__ v2,
    float* __restrict__ out)
{
    // XCD-chunked bijective swizzle: 1792 = 8 * 224. Consecutive row-groups of the
    // same image land on the same XCD -> halo row is an L2 hit.
    const int bid  = (blockIdx.x & 7) * 224 + (blockIdx.x >> 3);
    const int tile = bid & 1;
    const int gb   = bid >> 1;
    const int g    = gb % 56;          // row-pair group: output rows 2g, 2g+1
    const int b    = gb / 56;
    const int oh0  = 2 * g;
    const int ow0  = tile * 64;
    const int t    = threadIdx.x;

    // LDS: 2640 + 8704 + 4096 + 3072 + 512 = 19,024 B -> 8 blocks/CU LDS-limit
    __shared__ __align__(16) uint32_t s_xb[5][132];     // rows rel -1..3, col c = in-col-(2ow0-1)
    __shared__ __align__(16) uint32_t s_avg[2][16][68]; // [out-row r][ci2][local ow] (pad 68)
    __shared__ __align__(16) uint32_t s_wt2[16][64];
    __shared__ __align__(16) uint32_t s_wb[CO * 12];
    __shared__ float s_A1[CO], s_C[CO];

    // ---------------- Phase 0: weight staging (folded prep) ----------------
    for (int i = t; i < 16 * 64; i += 256) {
        int ci2 = i >> 6, co = i & 63;
        float inv2 = g2[co] * rsqrtf(v2[co] + EPS);
        s_wt2[ci2][co] = pack_h2(wds[co * CI + 2 * ci2]     * inv2,
                                 wds[co * CI + 2 * ci2 + 1] * inv2);
    }
    for (int i = t; i < CO * 9; i += 256) {
        int co = i / 9, k = i % 9;
        uint32_t bits = 0u;
#pragma unroll
        for (int ci = 0; ci < CI; ++ci)
            bits |= (uint32_t)(wbody[(co * CI + ci) * 9 + k] >= 0.0f) << ci;
        s_wb[co * 12 + k] = bits;
    }
    if (t < CO) {
        float inv1 = g1[t] * rsqrtf(v1[t] + EPS);
        float inv2 = g2[t] * rsqrtf(v2[t] + EPS);
        s_A1[t] = -2.0f * inv1;
        s_C[t]  = b1[t] - m1[t] * inv1 + b2[t] - m2[t] * inv2 + 288.0f * inv1;
    }

    // ---------------- Phase 1: derive bits + avgpool into LDS ----------------
    // Sub-phase A: 4 main input rows (2 pairs), all 256 threads.
    {
        const int pair = t >> 7;        // 0..1 -> input rows 2oh0+2p, 2oh0+2p+1
        const int q    = t & 3;         // ci quarter (ci = 8q..8q+7)
        const int f    = (t >> 2) & 31; // float4 col group: in-cols 2ow0+4f..+3
        const int jcol = 2 * ow0 + 4 * f;
        const bool colok = (jcol + 3 < WI);   // tile1 f>=24 is out of image (unused cols)
        const float* xp = x + ((size_t)(b * CI + 8 * q) * HI + (2 * oh0 + 2 * pair)) * WI + jcol;
        uint32_t m0[4] = {0, 0, 0, 0}, m1r[4] = {0, 0, 0, 0};
#pragma unroll
        for (int k = 0; k < 4; ++k) {
            const int c0 = 2 * k, c1 = c0 + 1;
            const int s0 = 8 * q + 2 * k, s1 = s0 + 1;
            float4 t0 = make_float4(0.f, 0.f, 0.f, 0.f);
            float4 u0 = t0, t1 = t0, u1 = t0;
            if (colok) {
                t0 = *(const float4*)(xp + (size_t)c0 * (HI * WI));
                u0 = *(const float4*)(xp + (size_t)c0 * (HI * WI) + WI);
                t1 = *(const float4*)(xp + (size_t)c1 * (HI * WI));
                u1 = *(const float4*)(xp + (size_t)c1 * (HI * WI) + WI);
            }
            m0[0]  |= ((uint32_t)(t0.x >= 0.f) << s0) | ((uint32_t)(t1.x >= 0.f) << s1);
            m0[1]  |= ((uint32_t)(t0.y >= 0.f) << s0) | ((uint32_t)(t1.y >= 0.f) << s1);
            m0[2]  |= ((uint32_t)(t0.z >= 0.f) << s0) | ((uint32_t)(t1.z >= 0.f) << s1);
            m0[3]  |= ((uint32_t)(t0.w >= 0.f) << s0) | ((uint32_t)(t1.w >= 0.f) << s1);
            m1r[0] |= ((uint32_t)(u0.x >= 0.f) << s0) | ((uint32_t)(u1.x >= 0.f) << s1);
            m1r[1] |= ((uint32_t)(u0.y >= 0.f) << s0) | ((uint32_t)(u1.y >= 0.f) << s1);
            m1r[2] |= ((uint32_t)(u0.z >= 0.f) << s0) | ((uint32_t)(u1.z >= 0.f) << s1);
            m1r[3] |= ((uint32_t)(u0.w >= 0.f) << s0) | ((uint32_t)(u1.w >= 0.f) << s1);
            // avgpool for ci2 = 4q+k at out-cols ow0+2f, ow0+2f+1
            float a0p0 = 0.25f * ((t0.x + t0.y) + (u0.x + u0.y));
            float a0p1 = 0.25f * ((t0.z + t0.w) + (u0.z + u0.w));
            float a1p0 = 0.25f * ((t1.x + t1.y) + (u1.x + u1.y));
            float a1p1 = 0.25f * ((t1.z + t1.w) + (u1.z + u1.w));
            *(uint2*)&s_avg[pair][4 * q + k][2 * f] =
                make_uint2(pack_h2(a0p0, a1p0), pack_h2(a0p1, a1p1));
        }
#pragma unroll
        for (int j = 0; j < 4; ++j) {
            m0[j]  |= __shfl_xor(m0[j], 1);  m0[j]  |= __shfl_xor(m0[j], 2);
            m1r[j] |= __shfl_xor(m1r[j], 1); m1r[j] |= __shfl_xor(m1r[j], 2);
        }
        uint32_t v0  = (q == 0) ? m0[0]  : (q == 1) ? m0[1]  : (q == 2) ? m0[2]  : m0[3];
        uint32_t v1v = (q == 0) ? m1r[0] : (q == 1) ? m1r[1] : (q == 2) ? m1r[2] : m1r[3];
        s_xb[1 + 2 * pair][1 + 4 * f + q] = v0;
        s_xb[2 + 2 * pair][1 + 4 * f + q] = v1v;
    }
    // Sub-phase B: halo row (LDS row 0 = input row 2oh0-1), threads 0..127.
    if (t < 128) {
        const int q = t & 3, f = t >> 2;
        const int jcol = 2 * ow0 + 4 * f;
        uint32_t mm[4] = {0, 0, 0, 0};
        if (g > 0 && jcol + 3 < WI) {
            const float* xp = x + ((size_t)(b * CI + 8 * q) * HI + (2 * oh0 - 1)) * WI + jcol;
#pragma unroll
            for (int k = 0; k < 4; ++k) {
                const int s0 = 8 * q + 2 * k, s1 = s0 + 1;
                const float4 t0 = *(const float4*)(xp + (size_t)(2 * k) * (HI * WI));
                const float4 t1 = *(const float4*)(xp + (size_t)(2 * k + 1) * (HI * WI));
                mm[0] |= ((uint32_t)(t0.x >= 0.f) << s0) | ((uint32_t)(t1.x >= 0.f) << s1);
                mm[1] |= ((uint32_t)(t0.y >= 0.f) << s0) | ((uint32_t)(t1.y >= 0.f) << s1);
                mm[2] |= ((uint32_t)(t0.z >= 0.f) << s0) | ((uint32_t)(t1.z >= 0.f) << s1);
                mm[3] |= ((uint32_t)(t0.w >= 0.f) << s0) | ((uint32_t)(t1.w >= 0.f) << s1);
            }
        }
#pragma unroll
        for (int j = 0; j < 4; ++j) { mm[j] |= __shfl_xor(mm[j], 1); mm[j] |= __shfl_xor(mm[j], 2); }
        s_xb[0][1 + 4 * f + q] = (q == 0) ? mm[0] : (q == 1) ? mm[1] : (q == 2) ? mm[2] : mm[3];
    }
    // Sub-phase C: halo column (c = 0, in-col 2ow0-1) for the 5 rows; 40 threads,
    // 4 channels each + 8-lane OR-butterfly.
    if (t < 40) {
        const int lr = t >> 3;          // LDS row 0..4 (abs input row 2oh0-1+lr)
        const int l  = t & 7;           // channels 4l..4l+3
        uint32_t bits = 0u;
        const int hr = 2 * oh0 - 1 + lr;
        const int wc = 2 * ow0 - 1;
        if (hr >= 0 && wc >= 0) {
            const float* xp = x + ((size_t)(b * CI + 4 * l) * HI + hr) * WI + wc;
#pragma unroll
            for (int ci = 0; ci < 4; ++ci)
                bits |= (uint32_t)(xp[(size_t)ci * (HI * WI)] >= 0.0f) << (4 * l + ci);
        }
        bits |= __shfl_xor(bits, 1);
        bits |= __shfl_xor(bits, 2);
        bits |= __shfl_xor(bits, 4);
        if (l == 0) s_xb[lr][0] = bits;
    }
    __syncthreads();

    // ---------------- Phase 2: compute (identical to proven main_kernel) ----------------
    const int cg  = t >> 4;     // 16 co-groups
    const int pg  = t & 15;     // 16 pixel-groups
    const int co0 = cg * 4;
    const int p0  = pg * 4;
    const bool pxvalid = (ow0 + p0 < WO);
    const bool px0 = (ow0 + p0 == 0);
    const int cbase = 8 * pg;

#pragma unroll 1
    for (int r = 0; r < 2; ++r) {
        // Downsample branch: 4co x 4pix dot2 tile over 16 ci-pairs
        float fa[4][4] = {{0.f,0.f,0.f,0.f},{0.f,0.f,0.f,0.f},{0.f,0.f,0.f,0.f},{0.f,0.f,0.f,0.f}};
#pragma unroll 4
        for (int ci2 = 0; ci2 < 16; ++ci2) {
            uint4 av = *(const uint4*)&s_avg[r][ci2][p0];
            uint4 wv = *(const uint4*)&s_wt2[ci2][co0];
            h2 a[4] = {as_h2(av.x), as_h2(av.y), as_h2(av.z), as_h2(av.w)};
            h2 w[4] = {as_h2(wv.x), as_h2(wv.y), as_h2(wv.z), as_h2(wv.w)};
#pragma unroll
            for (int jc = 0; jc < 4; ++jc)
#pragma unroll
                for (int jp = 0; jp < 4; ++jp)
                    fa[jc][jp] = __builtin_amdgcn_fdot2(w[jc], a[jp], fa[jc][jp], false);
        }

        // Body branch: taps c = cbase + 2*jp + kw, rows 2r + rI
        uint32_t xr[3][9];
#pragma unroll
        for (int rI = 0; rI < 3; ++rI) {
            const uint32_t* row = s_xb[2 * r + rI];
            uint4 a  = *(const uint4*)&row[cbase];
            uint4 bq = *(const uint4*)&row[cbase + 4];
            xr[rI][0] = a.x;  xr[rI][1] = a.y;  xr[rI][2] = a.z;  xr[rI][3] = a.w;
            xr[rI][4] = bq.x; xr[rI][5] = bq.y; xr[rI][6] = bq.z; xr[rI][7] = bq.w;
            xr[rI][8] = row[cbase + 8];
        }

        const bool oh0f = (g == 0 && r == 0);

        int sfin[4][4];
#pragma unroll
        for (int jc = 0; jc < 4; ++jc) {
            const int co = co0 + jc;
            uint4 wa  = *(const uint4*)&s_wb[co * 12];
            uint4 wb4 = *(const uint4*)&s_wb[co * 12 + 4];
            uint32_t wv[9] = {wa.x, wa.y, wa.z, wa.w, wb4.x, wb4.y, wb4.z, wb4.w,
                              s_wb[co * 12 + 8]};
#pragma unroll
            for (int jp = 0; jp < 4; ++jp) {
                int c00 = __popc(xr[0][2 * jp + 0] ^ wv[0]);
                int c01 = __popc(xr[0][2 * jp + 1] ^ wv[1]);
                int c02 = __popc(xr[0][2 * jp + 2] ^ wv[2]);
                int c10 = __popc(xr[1][2 * jp + 0] ^ wv[3]);
                int c11 = __popc(xr[1][2 * jp + 1] ^ wv[4]);
                int c12 = __popc(xr[1][2 * jp + 2] ^ wv[5]);
                int c20 = __popc(xr[2][2 * jp + 0] ^ wv[6]);
                int c21 = __popc(xr[2][2 * jp + 1] ^ wv[7]);
                int c22 = __popc(xr[2][2 * jp + 2] ^ wv[8]);
                int r0v  = c00 + c01 + c02;
                int ssum = r0v + c10 + c11 + c12 + c20 + c21 + c22;
                // zero-pad fixes: invalid taps count as 16 (-> 0 contribution)
                if (oh0f) ssum += 48 - r0v;              // top image row
                if (px0 && jp == 0) {                    // left image column
                    ssum += 48 - (c00 + c10 + c20);
                    if (oh0f) ssum += c00 - 16;          // corner double-fix
                }
                sfin[jc][jp] = ssum;
            }
        }

        if (pxvalid) {
#pragma unroll
            for (int jc = 0; jc < 4; ++jc) {
                const int co = co0 + jc;
                const float n2a = s_A1[co], cc = s_C[co];
                float4 o;
                o.x = fmaf(n2a, (float)sfin[jc][0], fa[jc][0] + cc);
                o.y = fmaf(n2a, (float)sfin[jc][1], fa[jc][1] + cc);
                o.z = fmaf(n2a, (float)sfin[jc][2], fa[jc][2] + cc);
                o.w = fmaf(n2a, (float)sfin[jc][3], fa[jc][3] + cc);
                *(float4*)&out[((size_t)(b * CO + co) * HO + (oh0 + r)) * WO + ow0 + p0] = o;
            }
        }
    }
}

extern "C" void kernel_launch(void* const* d_in, const int* in_sizes, int n_in,
                              void* d_out, int out_size, void* d_ws, size_t ws_size,
                              hipStream_t stream)
{
    (void)in_sizes; (void)n_in; (void)out_size; (void)d_ws; (void)ws_size;
    const float* x   = (const float*)d_in[0];
    const float* wbd = (const float*)d_in[1];
    const float* g1  = (const float*)d_in[2];
    const float* b1  = (const float*)d_in[3];
    const float* m1  = (const float*)d_in[4];
    const float* v1  = (const float*)d_in[5];
    const float* wds = (const float*)d_in[6];
    const float* g2  = (const float*)d_in[7];
    const float* b2  = (const float*)d_in[8];
    const float* m2  = (const float*)d_in[9];
    const float* v2  = (const float*)d_in[10];
    float* out = (float*)d_out;

    // grid = NB * 56 row-pair groups * 2 ow tiles = 1792 blocks (exactly 8*224)
    fused_kernel<<<dim3(NB * 56 * 2), 256, 0, stream>>>(
        x, wbd, g1, b1, m1, v1, wds, g2, b2, m2, v2, out);
}

// Round 2
// 49.592 us; speedup vs baseline: 1.2377x; 1.2377x over previous
//
#include <hip/hip_runtime.h>
#include <stdint.h>

// Problem constants
static constexpr int NB = 16;     // batch
static constexpr int CI = 32;     // in channels
static constexpr int CO = 64;     // out channels
static constexpr int HI = 224, WI = 224;
static constexpr int HO = 112, WO = 112;
static constexpr float EPS = 1e-5f;

typedef _Float16 h2 __attribute__((ext_vector_type(2)));

__device__ __forceinline__ h2 as_h2(uint32_t u) {
    union { uint32_t u; h2 h; } c; c.u = u; return c.h;
}
__device__ __forceinline__ uint32_t pack_h2(float a, float b) {
    union { uint32_t u; h2 h; } c;
    c.h = (h2){(_Float16)a, (_Float16)b};
    return c.u;
}

// Workspace layout (bytes): packed weights only.
// wbits : CO*12 u32 = 3072
// wt2   : 16*CO u32 = 4096   (end 7168)
// A1    : CO f32    = 256    (end 7424)
// Cc    : CO f32    = 256    (end 7680)
static constexpr size_t OFF_WT2 = 3072;
static constexpr size_t OFF_A1  = 7168;
static constexpr size_t OFF_CC  = 7424;
static constexpr size_t WS_NEED = 7680;

// Padded s_xb column index: breaks the pg-stride-32B 4-way bank conflict while
// keeping every phase-2 uint4 read 16B-aligned (cbase=8*pg -> idx 12*pg).
__device__ __forceinline__ int XB(int c) { return c + ((c >> 3) << 2); }
static constexpr int XBW = 132 + ((132 / 8) << 2) + 4;   // 200 u32 per row

__global__ __launch_bounds__(256) void prep_kernel(
    const float* __restrict__ wbody,
    const float* __restrict__ g1, const float* __restrict__ b1,
    const float* __restrict__ m1, const float* __restrict__ v1,
    const float* __restrict__ wds,
    const float* __restrict__ g2, const float* __restrict__ b2,
    const float* __restrict__ m2, const float* __restrict__ v2,
    uint32_t* __restrict__ wbits, uint32_t* __restrict__ wt2,
    float* __restrict__ A1, float* __restrict__ Cc)
{
    int i = blockIdx.x * 256 + threadIdx.x;
    if (i < 16 * CO) {
        // wt2[ci2][co] = half2(wds[co][2ci2], wds[co][2ci2+1]) * inv2[co]
        int ci2 = i >> 6, co = i & 63;
        float inv2 = g2[co] * rsqrtf(v2[co] + EPS);
        float w0 = wds[co * CI + 2 * ci2]     * inv2;
        float w1 = wds[co * CI + 2 * ci2 + 1] * inv2;
        wt2[i] = pack_h2(w0, w1);
    } else if (i < 16 * CO + CO * 9) {
        int j = i - 16 * CO;
        int co = j / 9, k = j % 9;
        uint32_t bits = 0u;
        for (int ci = 0; ci < CI; ++ci) {
            float wv = wbody[((co * CI + ci) * 3 + (k / 3)) * 3 + (k % 3)];
            bits |= (uint32_t)(wv >= 0.0f) << ci;
        }
        wbits[co * 12 + k] = bits;
    } else if (i < 16 * CO + CO * 9 + CO) {
        int co = i - 16 * CO - CO * 9;
        float inv1 = g1[co] * rsqrtf(v1[co] + EPS);
        float inv2 = g2[co] * rsqrtf(v2[co] + EPS);
        A1[co] = -2.0f * inv1;
        Cc[co] = b1[co] - m1[co] * inv1 + b2[co] - m2[co] * inv2 + 288.0f * inv1;
    } else if (i < 16 * CO + CO * 12) {
        // initialize the 3 pad words per co so the fused copy reads defined memory
        int j = i - 16 * CO - CO * 9 - CO + CO * 9 + CO;  // unused; keep simple below
        (void)j;
    }
}

// Fused derive+compute kernel. Per block = (b, output row-pair g, 64-wide ow tile).
//   Phase 0: coalesced copy of PRE-PACKED weights (7.7 KB) from workspace to LDS.
//   Phase 1: read the 5 needed input rows of x once, derive sign-bit masks (s_xb,
//            bank-conflict-padded) and 2x2 avgpool half2 ci-pairs (s_avg) into LDS.
//   Phase 2: proven popc body + fdot2 downsample, looped over the 2 output rows.
__global__ __launch_bounds__(256) void fused_kernel(
    const float* __restrict__ x,
    const uint32_t* __restrict__ wbits, const uint32_t* __restrict__ wt2,
    const float* __restrict__ A1, const float* __restrict__ Cc,
    float* __restrict__ out)
{
    // XCD-chunked bijective swizzle: 1792 = 8 * 224.
    const int bid  = (blockIdx.x & 7) * 224 + (blockIdx.x >> 3);
    const int tile = bid & 1;
    const int gb   = bid >> 1;
    const int g    = gb % 56;          // row-pair group: output rows 2g, 2g+1
    const int b    = gb / 56;
    const int oh0  = 2 * g;
    const int ow0  = tile * 64;
    const int t    = threadIdx.x;

    // LDS: 4000 + 8704 + 4096 + 3072 + 512 = 20,384 B -> 8 blocks/CU LDS-limit
    __shared__ __align__(16) uint32_t s_xb[5][XBW];     // rows rel -1..3, padded cols
    __shared__ __align__(16) uint32_t s_avg[2][16][68]; // [out-row r][ci2][local ow]
    __shared__ __align__(16) uint32_t s_wt2[16][64];
    __shared__ __align__(16) uint32_t s_wb[CO * 12];
    __shared__ float s_A1[CO], s_C[CO];

    // ---------------- Phase 0: coalesced packed-weight staging ----------------
    {
        uint32_t* wt2s = (uint32_t*)s_wt2;
#pragma unroll
        for (int i = 0; i < 4; ++i) wt2s[t + 256 * i] = wt2[t + 256 * i];
#pragma unroll
        for (int i = 0; i < 3; ++i) s_wb[t + 256 * i] = wbits[t + 256 * i];
        if (t < CO) { s_A1[t] = A1[t]; s_C[t] = Cc[t]; }
    }

    // ---------------- Phase 1: derive bits + avgpool into LDS ----------------
    // Sub-phase A: 4 main input rows (2 pairs), all 256 threads.
    {
        const int pair = t >> 7;        // 0..1 -> input rows 2oh0+2p, 2oh0+2p+1
        const int q    = t & 3;         // ci quarter (ci = 8q..8q+7)
        const int f    = (t >> 2) & 31; // float4 col group: in-cols 2ow0+4f..+3
        const int jcol = 2 * ow0 + 4 * f;
        const bool colok = (jcol + 3 < WI);
        const float* xp = x + ((size_t)(b * CI + 8 * q) * HI + (2 * oh0 + 2 * pair)) * WI + jcol;
        uint32_t m0[4] = {0, 0, 0, 0}, m1r[4] = {0, 0, 0, 0};
#pragma unroll
        for (int k = 0; k < 4; ++k) {
            const int c0 = 2 * k, c1 = c0 + 1;
            const int s0 = 8 * q + 2 * k, s1 = s0 + 1;
            float4 t0 = make_float4(0.f, 0.f, 0.f, 0.f);
            float4 u0 = t0, t1 = t0, u1 = t0;
            if (colok) {
                t0 = *(const float4*)(xp + (size_t)c0 * (HI * WI));
                u0 = *(const float4*)(xp + (size_t)c0 * (HI * WI) + WI);
                t1 = *(const float4*)(xp + (size_t)c1 * (HI * WI));
                u1 = *(const float4*)(xp + (size_t)c1 * (HI * WI) + WI);
            }
            m0[0]  |= ((uint32_t)(t0.x >= 0.f) << s0) | ((uint32_t)(t1.x >= 0.f) << s1);
            m0[1]  |= ((uint32_t)(t0.y >= 0.f) << s0) | ((uint32_t)(t1.y >= 0.f) << s1);
            m0[2]  |= ((uint32_t)(t0.z >= 0.f) << s0) | ((uint32_t)(t1.z >= 0.f) << s1);
            m0[3]  |= ((uint32_t)(t0.w >= 0.f) << s0) | ((uint32_t)(t1.w >= 0.f) << s1);
            m1r[0] |= ((uint32_t)(u0.x >= 0.f) << s0) | ((uint32_t)(u1.x >= 0.f) << s1);
            m1r[1] |= ((uint32_t)(u0.y >= 0.f) << s0) | ((uint32_t)(u1.y >= 0.f) << s1);
            m1r[2] |= ((uint32_t)(u0.z >= 0.f) << s0) | ((uint32_t)(u1.z >= 0.f) << s1);
            m1r[3] |= ((uint32_t)(u0.w >= 0.f) << s0) | ((uint32_t)(u1.w >= 0.f) << s1);
            float a0p0 = 0.25f * ((t0.x + t0.y) + (u0.x + u0.y));
            float a0p1 = 0.25f * ((t0.z + t0.w) + (u0.z + u0.w));
            float a1p0 = 0.25f * ((t1.x + t1.y) + (u1.x + u1.y));
            float a1p1 = 0.25f * ((t1.z + t1.w) + (u1.z + u1.w));
            *(uint2*)&s_avg[pair][4 * q + k][2 * f] =
                make_uint2(pack_h2(a0p0, a1p0), pack_h2(a0p1, a1p1));
        }
#pragma unroll
        for (int j = 0; j < 4; ++j) {
            m0[j]  |= __shfl_xor(m0[j], 1);  m0[j]  |= __shfl_xor(m0[j], 2);
            m1r[j] |= __shfl_xor(m1r[j], 1); m1r[j] |= __shfl_xor(m1r[j], 2);
        }
        uint32_t v0  = (q == 0) ? m0[0]  : (q == 1) ? m0[1]  : (q == 2) ? m0[2]  : m0[3];
        uint32_t v1v = (q == 0) ? m1r[0] : (q == 1) ? m1r[1] : (q == 2) ? m1r[2] : m1r[3];
        s_xb[1 + 2 * pair][XB(1 + 4 * f + q)] = v0;
        s_xb[2 + 2 * pair][XB(1 + 4 * f + q)] = v1v;
    }
    // Sub-phase B: halo row (LDS row 0 = input row 2oh0-1), threads 0..127.
    if (t < 128) {
        const int q = t & 3, f = t >> 2;
        const int jcol = 2 * ow0 + 4 * f;
        uint32_t mm[4] = {0, 0, 0, 0};
        if (g > 0 && jcol + 3 < WI) {
            const float* xp = x + ((size_t)(b * CI + 8 * q) * HI + (2 * oh0 - 1)) * WI + jcol;
#pragma unroll
            for (int k = 0; k < 4; ++k) {
                const int s0 = 8 * q + 2 * k, s1 = s0 + 1;
                const float4 t0 = *(const float4*)(xp + (size_t)(2 * k) * (HI * WI));
                const float4 t1 = *(const float4*)(xp + (size_t)(2 * k + 1) * (HI * WI));
                mm[0] |= ((uint32_t)(t0.x >= 0.f) << s0) | ((uint32_t)(t1.x >= 0.f) << s1);
                mm[1] |= ((uint32_t)(t0.y >= 0.f) << s0) | ((uint32_t)(t1.y >= 0.f) << s1);
                mm[2] |= ((uint32_t)(t0.z >= 0.f) << s0) | ((uint32_t)(t1.z >= 0.f) << s1);
                mm[3] |= ((uint32_t)(t0.w >= 0.f) << s0) | ((uint32_t)(t1.w >= 0.f) << s1);
            }
        }
#pragma unroll
        for (int j = 0; j < 4; ++j) { mm[j] |= __shfl_xor(mm[j], 1); mm[j] |= __shfl_xor(mm[j], 2); }
        s_xb[0][XB(1 + 4 * f + q)] = (q == 0) ? mm[0] : (q == 1) ? mm[1] : (q == 2) ? mm[2] : mm[3];
    }
    // Sub-phase C: halo column (c = 0, in-col 2ow0-1) for the 5 rows.
    if (t < 40) {
        const int lr = t >> 3;          // LDS row 0..4 (abs input row 2oh0-1+lr)
        const int l  = t & 7;           // channels 4l..4l+3
        uint32_t bits = 0u;
        const int hr = 2 * oh0 - 1 + lr;
        const int wc = 2 * ow0 - 1;
        if (hr >= 0 && wc >= 0) {
            const float* xp = x + ((size_t)(b * CI + 4 * l) * HI + hr) * WI + wc;
#pragma unroll
            for (int ci = 0; ci < 4; ++ci)
                bits |= (uint32_t)(xp[(size_t)ci * (HI * WI)] >= 0.0f) << (4 * l + ci);
        }
        bits |= __shfl_xor(bits, 1);
        bits |= __shfl_xor(bits, 2);
        bits |= __shfl_xor(bits, 4);
        if (l == 0) s_xb[lr][XB(0)] = bits;
    }
    __syncthreads();

    // ---------------- Phase 2: compute (proven main_kernel body) ----------------
    const int cg  = t >> 4;     // 16 co-groups
    const int pg  = t & 15;     // 16 pixel-groups
    const int co0 = cg * 4;
    const int p0  = pg * 4;
    const bool pxvalid = (ow0 + p0 < WO);
    const bool px0 = (ow0 + p0 == 0);
    const int cb = 12 * pg;     // XB(8*pg)

#pragma unroll 1
    for (int r = 0; r < 2; ++r) {
        // Downsample branch: 4co x 4pix dot2 tile over 16 ci-pairs
        float fa[4][4] = {{0.f,0.f,0.f,0.f},{0.f,0.f,0.f,0.f},{0.f,0.f,0.f,0.f},{0.f,0.f,0.f,0.f}};
#pragma unroll 4
        for (int ci2 = 0; ci2 < 16; ++ci2) {
            uint4 av = *(const uint4*)&s_avg[r][ci2][p0];
            uint4 wv = *(const uint4*)&s_wt2[ci2][co0];
            h2 a[4] = {as_h2(av.x), as_h2(av.y), as_h2(av.z), as_h2(av.w)};
            h2 w[4] = {as_h2(wv.x), as_h2(wv.y), as_h2(wv.z), as_h2(wv.w)};
#pragma unroll
            for (int jc = 0; jc < 4; ++jc)
#pragma unroll
                for (int jp = 0; jp < 4; ++jp)
                    fa[jc][jp] = __builtin_amdgcn_fdot2(w[jc], a[jp], fa[jc][jp], false);
        }

        // Body branch: taps c = 8*pg + 2*jp + kw -> padded idx cb + 2*jp + kw
        uint32_t xr[3][9];
#pragma unroll
        for (int rI = 0; rI < 3; ++rI) {
            const uint32_t* row = s_xb[2 * r + rI];
            uint4 a  = *(const uint4*)&row[cb];
            uint4 bq = *(const uint4*)&row[cb + 4];
            xr[rI][0] = a.x;  xr[rI][1] = a.y;  xr[rI][2] = a.z;  xr[rI][3] = a.w;
            xr[rI][4] = bq.x; xr[rI][5] = bq.y; xr[rI][6] = bq.z; xr[rI][7] = bq.w;
            xr[rI][8] = row[cb + 12];   // XB(8*pg + 8)
        }

        const bool oh0f = (g == 0 && r == 0);

        int sfin[4][4];
#pragma unroll
        for (int jc = 0; jc < 4; ++jc) {
            const int co = co0 + jc;
            uint4 wa  = *(const uint4*)&s_wb[co * 12];
            uint4 wb4 = *(const uint4*)&s_wb[co * 12 + 4];
            uint32_t wv[9] = {wa.x, wa.y, wa.z, wa.w, wb4.x, wb4.y, wb4.z, wb4.w,
                              s_wb[co * 12 + 8]};
#pragma unroll
            for (int jp = 0; jp < 4; ++jp) {
                int c00 = __popc(xr[0][2 * jp + 0] ^ wv[0]);
                int c01 = __popc(xr[0][2 * jp + 1] ^ wv[1]);
                int c02 = __popc(xr[0][2 * jp + 2] ^ wv[2]);
                int c10 = __popc(xr[1][2 * jp + 0] ^ wv[3]);
                int c11 = __popc(xr[1][2 * jp + 1] ^ wv[4]);
                int c12 = __popc(xr[1][2 * jp + 2] ^ wv[5]);
                int c20 = __popc(xr[2][2 * jp + 0] ^ wv[6]);
                int c21 = __popc(xr[2][2 * jp + 1] ^ wv[7]);
                int c22 = __popc(xr[2][2 * jp + 2] ^ wv[8]);
                int r0v  = c00 + c01 + c02;
                int ssum = r0v + c10 + c11 + c12 + c20 + c21 + c22;
                // zero-pad fixes: invalid taps count as 16 (-> 0 contribution)
                if (oh0f) ssum += 48 - r0v;              // top image row
                if (px0 && jp == 0) {                    // left image column
                    ssum += 48 - (c00 + c10 + c20);
                    if (oh0f) ssum += c00 - 16;          // corner double-fix
                }
                sfin[jc][jp] = ssum;
            }
        }

        if (pxvalid) {
#pragma unroll
            for (int jc = 0; jc < 4; ++jc) {
                const int co = co0 + jc;
                const float n2a = s_A1[co], cc = s_C[co];
                float4 o;
                o.x = fmaf(n2a, (float)sfin[jc][0], fa[jc][0] + cc);
                o.y = fmaf(n2a, (float)sfin[jc][1], fa[jc][1] + cc);
                o.z = fmaf(n2a, (float)sfin[jc][2], fa[jc][2] + cc);
                o.w = fmaf(n2a, (float)sfin[jc][3], fa[jc][3] + cc);
                *(float4*)&out[((size_t)(b * CO + co) * HO + (oh0 + r)) * WO + ow0 + p0] = o;
            }
        }
    }
}

// Fallback if workspace is too small: direct per-output computation (slow, correct).
__global__ __launch_bounds__(256) void naive_kernel(
    const float* __restrict__ x, const float* __restrict__ wbody,
    const float* __restrict__ g1, const float* __restrict__ b1,
    const float* __restrict__ m1, const float* __restrict__ v1,
    const float* __restrict__ wds,
    const float* __restrict__ g2, const float* __restrict__ b2,
    const float* __restrict__ m2, const float* __restrict__ v2,
    float* __restrict__ out)
{
    int i = blockIdx.x * 256 + threadIdx.x;
    if (i >= NB * CO * HO * WO) return;
    int ow = i % WO;
    int oh = (i / WO) % HO;
    int co = (i / (WO * HO)) % CO;
    int b  = i / (WO * HO * CO);
    float inv1 = g1[co] * rsqrtf(v1[co] + EPS);
    float inv2 = g2[co] * rsqrtf(v2[co] + EPS);
    int body = 0;
    float ds = 0.f;
    for (int ci = 0; ci < CI; ++ci) {
        const float* xp = x + (size_t)(b * CI + ci) * (HI * WI);
        for (int kh = 0; kh < 3; ++kh) {
            int hh = 2 * oh - 1 + kh;
            if (hh < 0 || hh >= HI) continue;
            for (int kw = 0; kw < 3; ++kw) {
                int ww = 2 * ow - 1 + kw;
                if (ww < 0 || ww >= WI) continue;
                float xv = xp[(size_t)hh * WI + ww];
                float wv = wbody[((co * CI + ci) * 3 + kh) * 3 + kw];
                int sx = (xv >= 0.f) ? 1 : -1;
                int sw = (wv >= 0.f) ? 1 : -1;
                body += sx * sw;
            }
        }
        float a = 0.25f * (xp[(size_t)(2 * oh) * WI + 2 * ow]
                         + xp[(size_t)(2 * oh) * WI + 2 * ow + 1]
                         + xp[(size_t)(2 * oh + 1) * WI + 2 * ow]
                         + xp[(size_t)(2 * oh + 1) * WI + 2 * ow + 1]);
        ds += a * wds[co * CI + ci];
    }
    out[i] = inv1 * (float)body + (b1[co] - m1[co] * inv1)
           + inv2 * ds + (b2[co] - m2[co] * inv2);
}

extern "C" void kernel_launch(void* const* d_in, const int* in_sizes, int n_in,
                              void* d_out, int out_size, void* d_ws, size_t ws_size,
                              hipStream_t stream)
{
    (void)in_sizes; (void)n_in; (void)out_size;
    const float* x   = (const float*)d_in[0];
    const float* wbd = (const float*)d_in[1];
    const float* g1  = (const float*)d_in[2];
    const float* b1  = (const float*)d_in[3];
    const float* m1  = (const float*)d_in[4];
    const float* v1  = (const float*)d_in[5];
    const float* wds = (const float*)d_in[6];
    const float* g2  = (const float*)d_in[7];
    const float* b2  = (const float*)d_in[8];
    const float* m2  = (const float*)d_in[9];
    const float* v2  = (const float*)d_in[10];
    float* out = (float*)d_out;

    if (ws_size < WS_NEED) {
        int total = NB * CO * HO * WO;
        naive_kernel<<<(total + 255) / 256, 256, 0, stream>>>(
            x, wbd, g1, b1, m1, v1, wds, g2, b2, m2, v2, out);
        return;
    }

    char* wsb = (char*)d_ws;
    uint32_t* wbits = (uint32_t*)wsb;
    uint32_t* wt2   = (uint32_t*)(wsb + OFF_WT2);
    float*    A1    = (float*)(wsb + OFF_A1);
    float*    Cc    = (float*)(wsb + OFF_CC);

    prep_kernel<<<7, 256, 0, stream>>>(wbd, g1, b1, m1, v1, wds, g2, b2, m2, v2,
                                       wbits, wt2, A1, Cc);
    // grid = NB * 56 row-pair groups * 2 ow tiles = 1792 blocks (exactly 8*224)
    fused_kernel<<<dim3(NB * 56 * 2), 256, 0, stream>>>(
        x, wbits, wt2, A1, Cc, out);
}